// Round 1
// baseline (417.413 us; speedup 1.0000x reference)
//
#include <hip/hip_runtime.h>

// TSM shift: x shape (B=4, T=16, H=64, W=64, C=256) fp32, row-major, C contiguous.
// out[b,t,h,w,c] = x[b,t+1,h,w,c]  for c in [0,64)    (0 if t+1 == T)
//                = x[b,t-1,h,w,c]  for c in [64,128)  (0 if t == 0)
//                = x[b,t,  h,w,c]  for c in [128,256)
//
// float4 view: 64 float4 per (b,t,h,w) row; t-stride = H*W*C/4 = 262144 float4.

#define T_DIM 16
#define TSTRIDE4 262144   // H*W*C/4 = 64*64*256/4
#define ROW4_LOG2 6       // 256/4 = 64 float4 per channel row
#define HW_LOG2 12        // H*W = 4096

__global__ __launch_bounds__(256) void tsm_kernel(const float4* __restrict__ x,
                                                  float4* __restrict__ out,
                                                  unsigned int n4) {
    unsigned int idx = blockIdx.x * 256u + threadIdx.x;
    if (idx >= n4) return;

    unsigned int c4  = idx & 63u;                      // float4 index within channel row
    unsigned int row = idx >> ROW4_LOG2;               // (b,t,h,w) flat
    unsigned int t   = (row >> HW_LOG2) & (T_DIM - 1); // T index

    unsigned int src = idx;
    bool zero = false;
    if (c4 < 16u) {               // channels [0,64): shift fwd (read t+1)
        src  = idx + TSTRIDE4;
        zero = (t == T_DIM - 1);
    } else if (c4 < 32u) {        // channels [64,128): shift bwd (read t-1)
        src  = idx - TSTRIDE4;
        zero = (t == 0);
    }
    // channels [128,256): identity

    float4 v;
    if (zero) {
        v = make_float4(0.f, 0.f, 0.f, 0.f);
    } else {
        v = x[src];
    }
    out[idx] = v;
}

extern "C" void kernel_launch(void* const* d_in, const int* in_sizes, int n_in,
                              void* d_out, int out_size, void* d_ws, size_t ws_size,
                              hipStream_t stream) {
    const float4* x   = (const float4*)d_in[0];
    float4*       out = (float4*)d_out;
    unsigned int n4 = (unsigned int)(out_size / 4);    // 16,777,216 float4s
    unsigned int blocks = (n4 + 255u) / 256u;          // 65,536 blocks
    tsm_kernel<<<dim3(blocks), dim3(256), 0, stream>>>(x, out, n4);
}

// Round 2
// 412.828 us; speedup vs baseline: 1.0111x; 1.0111x over previous
//
#include <hip/hip_runtime.h>

// TSM shift: x shape (B=4, T=16, H=64, W=64, C=256) fp32, row-major, C contiguous.
// out[b,t,h,w,c] = x[b,t+1,h,w,c]  for c in [0,64)    (0 if t == 15)
//                = x[b,t-1,h,w,c]  for c in [64,128)  (0 if t == 0)
//                = x[b,t,  h,w,c]  for c in [128,256)
//
// float4 view: 64 float4 per (b,t,h,w) row; t-stride = H*W*C/4 = 262144 float4.
// idx layout: idx = (((b*16+t)*4096 + hw)*64 + c4)  →  c4 = idx&63, t = (idx>>18)&15.

typedef float v4f __attribute__((ext_vector_type(4)));

#define TSTRIDE4 262144
#define ELEMS_PER_THREAD 4

__global__ __launch_bounds__(256) void tsm_kernel(const v4f* __restrict__ x,
                                                  v4f* __restrict__ out,
                                                  unsigned int n4) {
    unsigned int stride = gridDim.x * 256u;
    for (unsigned int idx = blockIdx.x * 256u + threadIdx.x; idx < n4; idx += stride) {
        unsigned int c4 = idx & 63u;               // float4 index within channel row
        unsigned int t  = (idx >> 18) & 15u;       // T index

        // Branchless segment select: fwd (c4<16) reads t+1, bwd (16<=c4<32) reads t-1,
        // identity otherwise. Boundary slices produce zero without loading.
        bool fwd = (c4 < 16u);
        bool bwd = (c4 >= 16u) & (c4 < 32u);
        int off  = fwd ? TSTRIDE4 : (bwd ? -TSTRIDE4 : 0);
        bool zero = (fwd & (t == 15u)) | (bwd & (t == 0u));

        v4f v = (v4f)(0.0f);
        if (!zero) v = __builtin_nontemporal_load(&x[(int)idx + off]);
        __builtin_nontemporal_store(v, &out[idx]);
    }
}

extern "C" void kernel_launch(void* const* d_in, const int* in_sizes, int n_in,
                              void* d_out, int out_size, void* d_ws, size_t ws_size,
                              hipStream_t stream) {
    const v4f* x   = (const v4f*)d_in[0];
    v4f*       out = (v4f*)d_out;
    unsigned int n4 = (unsigned int)(out_size / 4);              // 16,777,216 float4s
    unsigned int threads_total = n4 / ELEMS_PER_THREAD;          // 4,194,304 threads
    unsigned int blocks = threads_total / 256u;                  // 16,384 blocks
    tsm_kernel<<<dim3(blocks), dim3(256), 0, stream>>>(x, out, n4);
}